// Round 1
// 806.176 us; speedup vs baseline: 6.7224x; 6.7224x over previous
//
#include <hip/hip_runtime.h>
#include <hip/hip_bf16.h>

#define NH 16
#define HD 64
#define ED 1024
#define BS 4
#define SL 2048

typedef _Float16 f16x8 __attribute__((ext_vector_type(8)));
typedef _Float16 f16x2 __attribute__((ext_vector_type(2)));
typedef float floatx4 __attribute__((ext_vector_type(4)));

// ---------------------------------------------------------------------------
// GEMM: C = A[MxK] * B[NxK]^T. fp32 global inputs converted to fp16 during
// LDS staging; MFMA f32_16x16x32_f16; fp32 accumulate.
// 64x64 tile per 256-thread block; 4 waves 2x2, each wave 32x32 (2x2 mfma).
// LDS fragment-contiguous: lane's 16B fragment at lds[(mt*64+lane)*8].
// A_MODE 0: A fp32 row-major [M x K]
// A_MODE 1: A fp16 [b,h,s,d]  (row = b*SL+s, k = h*64+d) — attn-out gather
// OUT_MODE 0: fp16 scatter to [b,h,s,d]
// OUT_MODE 1: fp32 row-major [M x N]
// ---------------------------------------------------------------------------
template <int A_MODE, int OUT_MODE>
__device__ __forceinline__ void gemm_bt_body(const float* __restrict__ Af,
                                             const _Float16* __restrict__ Ah,
                                             const float* __restrict__ B,
                                             _Float16* __restrict__ outH,
                                             float* __restrict__ outF,
                                             int K, int N)
{
    __shared__ __align__(16) _Float16 As[64 * 32];
    __shared__ __align__(16) _Float16 Bs[64 * 32];

    const int tid  = threadIdx.x;
    const int wave = tid >> 6;
    const int lane = tid & 63;
    const int wm = wave >> 1;
    const int wn = wave & 1;
    const int rowTile = blockIdx.y * 64;
    const int colTile = blockIdx.x * 64;

    const int sRow  = tid >> 2;   // 0..63 tile row
    const int sQuad = tid & 3;    // which k-octet
    const int ldsOff = ((sRow >> 4) * 64 + (sRow & 15) + 16 * sQuad) * 8;

    const int aRow = rowTile + sRow;
    const int aB = aRow >> 11;          // / SL
    const int aS = aRow & (SL - 1);

    floatx4 acc00 = {0.f, 0.f, 0.f, 0.f};
    floatx4 acc01 = {0.f, 0.f, 0.f, 0.f};
    floatx4 acc10 = {0.f, 0.f, 0.f, 0.f};
    floatx4 acc11 = {0.f, 0.f, 0.f, 0.f};

    for (int kb = 0; kb < K; kb += 32) {
        const int k0 = kb + sQuad * 8;
        f16x8 av;
        if (A_MODE == 0) {
            float4 a0 = *(const float4*)(Af + (size_t)aRow * K + k0);
            float4 a1 = *(const float4*)(Af + (size_t)aRow * K + k0 + 4);
            av[0] = (_Float16)a0.x; av[1] = (_Float16)a0.y;
            av[2] = (_Float16)a0.z; av[3] = (_Float16)a0.w;
            av[4] = (_Float16)a1.x; av[5] = (_Float16)a1.y;
            av[6] = (_Float16)a1.z; av[7] = (_Float16)a1.w;
        } else {
            av = *(const f16x8*)(Ah + ((((size_t)(aB * NH + (k0 >> 6))) * SL + aS) * HD + (k0 & (HD - 1))));
        }
        float4 b0 = *(const float4*)(B + (size_t)(colTile + sRow) * K + k0);
        float4 b1 = *(const float4*)(B + (size_t)(colTile + sRow) * K + k0 + 4);
        f16x8 bv;
        bv[0] = (_Float16)b0.x; bv[1] = (_Float16)b0.y;
        bv[2] = (_Float16)b0.z; bv[3] = (_Float16)b0.w;
        bv[4] = (_Float16)b1.x; bv[5] = (_Float16)b1.y;
        bv[6] = (_Float16)b1.z; bv[7] = (_Float16)b1.w;

        __syncthreads();                       // protect prior frag reads
        *(f16x8*)(As + ldsOff) = av;
        *(f16x8*)(Bs + ldsOff) = bv;
        __syncthreads();
        f16x8 a0v = *(const f16x8*)(As + ((wm * 2 + 0) * 64 + lane) * 8);
        f16x8 a1v = *(const f16x8*)(As + ((wm * 2 + 1) * 64 + lane) * 8);
        f16x8 b0v = *(const f16x8*)(Bs + ((wn * 2 + 0) * 64 + lane) * 8);
        f16x8 b1v = *(const f16x8*)(Bs + ((wn * 2 + 1) * 64 + lane) * 8);
        acc00 = __builtin_amdgcn_mfma_f32_16x16x32_f16(a0v, b0v, acc00, 0, 0, 0);
        acc01 = __builtin_amdgcn_mfma_f32_16x16x32_f16(a0v, b1v, acc01, 0, 0, 0);
        acc10 = __builtin_amdgcn_mfma_f32_16x16x32_f16(a1v, b0v, acc10, 0, 0, 0);
        acc11 = __builtin_amdgcn_mfma_f32_16x16x32_f16(a1v, b1v, acc11, 0, 0, 0);
    }

    const int rBase = rowTile + wm * 32 + ((lane >> 4) * 4);
    const int cBase = colTile + wn * 32 + (lane & 15);
    floatx4 accs[2][2] = {{acc00, acc01}, {acc10, acc11}};
#pragma unroll
    for (int mi = 0; mi < 2; mi++) {
#pragma unroll
        for (int ni = 0; ni < 2; ni++) {
            int col = cBase + ni * 16;
#pragma unroll
            for (int i = 0; i < 4; i++) {
                int row = rBase + mi * 16 + i;
                float v = accs[mi][ni][i];
                if (OUT_MODE == 0) {
                    int b = row >> 11;          // / SL
                    int s = row & (SL - 1);
                    int h = col >> 6;           // / HD
                    int d = col & (HD - 1);
                    outH[(((size_t)(b * NH + h)) * SL + s) * HD + d] = (_Float16)v;
                } else {
                    outF[(size_t)row * N + col] = v;
                }
            }
        }
    }
}

__global__ __launch_bounds__(256) void qkv_kernel(const float* __restrict__ x,
                                                  const float* __restrict__ Wq,
                                                  const float* __restrict__ Wk,
                                                  const float* __restrict__ Wv,
                                                  _Float16* __restrict__ Q,
                                                  _Float16* __restrict__ Kk,
                                                  _Float16* __restrict__ V)
{
    const float* W = (blockIdx.z == 0) ? Wq : (blockIdx.z == 1) ? Wk : Wv;
    _Float16* out = (blockIdx.z == 0) ? Q : (blockIdx.z == 1) ? Kk : V;
    gemm_bt_body<0, 0>(x, nullptr, W, out, nullptr, ED, ED);
}

__global__ __launch_bounds__(256) void oproj_kernel(const _Float16* __restrict__ A,
                                                    const float* __restrict__ Wo,
                                                    float* __restrict__ out)
{
    gemm_bt_body<1, 1>(nullptr, A, Wo, nullptr, out, ED, ED);
}

// ---------------------------------------------------------------------------
// MFMA flash attention.
// Block = 256 threads = 4 waves; q-tile 128 rows (wave owns 32 = 2 m-tiles).
// KV chunk = 64 keys. Per wave per chunk: 16 QK^T MFMAs + 16 PV MFMAs
// (mfma_f32_16x16x32_f16, fp32 accum).
// LDS:
//   Ks: K chunk in fragment-contiguous layout (8 subtiles x 1KB) — lane l's
//       frag at subtile + l*16B => conflict-free b128 reads AND writes.
//   Vt: V^T [d][key], 128B row stride, octet XOR-swizzled
//       (oct ^= (d&7)^((d>>3)&7)) => ~2-way conflicts on 4B paired-key
//       writes and on b128 frag reads.
//   Ps: per-wave P tile [32q][64k], octet XOR-swizzled
//       (oct ^= (q&7)^(((q>>3)&3)<<1)) — acc->A-frag redistribution, no
//       cross-wave barrier needed (per-wave private region).
// Bias added from global fp32 (dominant, 64B-coalesced HBM stream).
// Online softmax in the MFMA C-layout: row = q = (lane>>4)*4+reg,
// col = key/d = lane&15; row reductions are shfl_xor {1,2,4,8}.
// Grid (BS, SL/128, NH): batch fastest => the 4 batches sharing a bias panel
// run adjacently => bias fetched ~once from HBM, re-served by L2/L3.
// ---------------------------------------------------------------------------
__global__ __launch_bounds__(256) void attn_kernel(const _Float16* __restrict__ Qg,
                                                   const _Float16* __restrict__ Kg,
                                                   const _Float16* __restrict__ Vg,
                                                   const float* __restrict__ bias,
                                                   _Float16* __restrict__ attnOut)
{
    __shared__ __align__(16) _Float16 Ks[8 * 64 * 8];    // 8 KB
    __shared__ __align__(16) _Float16 Vt[64 * 64];       // 8 KB
    __shared__ __align__(16) _Float16 Ps[4 * 32 * 64];   // 16 KB

    const int b  = blockIdx.x;
    const int qt = blockIdx.y;
    const int h  = blockIdx.z;
    const int bh = b * NH + h;
    const int tid  = threadIdx.x;
    const int wave = tid >> 6;
    const int lane = tid & 63;
    const int lo16 = lane & 15;
    const int hi4  = lane >> 4;

    const _Float16* Qbh = Qg + (size_t)bh * SL * HD;
    const _Float16* Kbh = Kg + (size_t)bh * SL * HD;
    const _Float16* Vbh = Vg + (size_t)bh * SL * HD;
    const float* biasH = bias + (size_t)h * SL * SL;

    const int q0 = qt * 128 + wave * 32;

    // Q fragments, held in registers for the whole kernel: qf[m][ks]
    // A-frag layout: lane l -> row = l&15, k = (l>>4)*8 + j  (k-step ks*32)
    f16x8 qf[2][2];
#pragma unroll
    for (int m = 0; m < 2; m++)
#pragma unroll
        for (int ks = 0; ks < 2; ks++)
            qf[m][ks] = *(const f16x8*)(Qbh + (size_t)(q0 + m * 16 + lo16) * HD
                                        + ks * 32 + hi4 * 8);

    floatx4 oAcc[2][4];
    float mRow[2][4], lRow[2][4];
#pragma unroll
    for (int m = 0; m < 2; m++)
#pragma unroll
        for (int n = 0; n < 4; n++)
            oAcc[m][n] = (floatx4){0.f, 0.f, 0.f, 0.f};
#pragma unroll
    for (int m = 0; m < 2; m++)
#pragma unroll
        for (int r = 0; r < 4; r++) { mRow[m][r] = -1e30f; lRow[m][r] = 0.f; }

    // staging maps
    const int kKey = tid >> 2;          // 0..63
    const int kD0  = (tid & 3) * 8;     // 0,8,16,24 (second load +32)
    _Float16* kDst0 = Ks + (((kKey >> 4)     ) * 64 + (kKey & 15) + 16 * (kD0 >> 3)) * 8;
    _Float16* kDst1 = Ks + (((kKey >> 4) + 4) * 64 + (kKey & 15) + 16 * (kD0 >> 3)) * 8;

    const int vK0 = (tid >> 3) * 2;     // even key 0..62 (pair k0,k0+1)
    const int vD0 = (tid & 7) * 8;      // 0..56

    for (int kc = 0; kc < SL; kc += 64) {
        // issue global loads before the barrier (latency hides under sync)
        f16x8 ka = *(const f16x8*)(Kbh + (size_t)(kc + kKey) * HD + kD0);
        f16x8 kb = *(const f16x8*)(Kbh + (size_t)(kc + kKey) * HD + kD0 + 32);
        f16x8 va = *(const f16x8*)(Vbh + (size_t)(kc + vK0    ) * HD + vD0);
        f16x8 vb = *(const f16x8*)(Vbh + (size_t)(kc + vK0 + 1) * HD + vD0);

        __syncthreads();                 // prior chunk's LDS reads complete
        *(f16x8*)kDst0 = ka;
        *(f16x8*)kDst1 = kb;
#pragma unroll
        for (int i = 0; i < 8; i++) {
            const int d = vD0 + i;
            const int sw = (d & 7) ^ ((d >> 3) & 7);
            char* p = (char*)Vt + (d << 7)
                      + ((((vK0 >> 3) ^ sw) & 7) << 4) + ((vK0 & 7) << 1);
            f16x2 pr; pr[0] = va[i]; pr[1] = vb[i];
            *(f16x2*)p = pr;
        }
        __syncthreads();                 // staging visible

        // ---- S = Q K^T  (per wave: 32q x 64k) ----
        floatx4 s[2][4];
#pragma unroll
        for (int m = 0; m < 2; m++)
#pragma unroll
            for (int n = 0; n < 4; n++)
                s[m][n] = (floatx4){0.f, 0.f, 0.f, 0.f};
#pragma unroll
        for (int ks = 0; ks < 2; ks++)
#pragma unroll
            for (int n = 0; n < 4; n++) {
                f16x8 kf = *(const f16x8*)(Ks + ((ks * 4 + n) * 64 + lane) * 8);
                s[0][n] = __builtin_amdgcn_mfma_f32_16x16x32_f16(qf[0][ks], kf, s[0][n], 0, 0, 0);
                s[1][n] = __builtin_amdgcn_mfma_f32_16x16x32_f16(qf[1][ks], kf, s[1][n], 0, 0, 0);
            }

        // ---- bias + online softmax; P -> f16 -> per-wave LDS ----
#pragma unroll
        for (int m = 0; m < 2; m++)
#pragma unroll
            for (int r = 0; r < 4; r++) {
                const int ql = m * 16 + hi4 * 4 + r;     // wave-local q 0..31
                const float* bp = biasH + (size_t)(q0 + ql) * SL + kc + lo16;
                float s0 = s[m][0][r] + bp[0];
                float s1 = s[m][1][r] + bp[16];
                float s2 = s[m][2][r] + bp[32];
                float s3 = s[m][3][r] + bp[48];
                float rmax = fmaxf(fmaxf(s0, s1), fmaxf(s2, s3));
                rmax = fmaxf(rmax, __shfl_xor(rmax, 1));
                rmax = fmaxf(rmax, __shfl_xor(rmax, 2));
                rmax = fmaxf(rmax, __shfl_xor(rmax, 4));
                rmax = fmaxf(rmax, __shfl_xor(rmax, 8));
                const float mOld = mRow[m][r];
                const float mNew = fmaxf(mOld, rmax);
                const float alpha = __expf(mOld - mNew);
                mRow[m][r] = mNew;
                float p0 = __expf(s0 - mNew);
                float p1 = __expf(s1 - mNew);
                float p2 = __expf(s2 - mNew);
                float p3 = __expf(s3 - mNew);
                float rsum = (p0 + p1) + (p2 + p3);
                rsum += __shfl_xor(rsum, 1);
                rsum += __shfl_xor(rsum, 2);
                rsum += __shfl_xor(rsum, 4);
                rsum += __shfl_xor(rsum, 8);
                lRow[m][r] = lRow[m][r] * alpha + rsum;
#pragma unroll
                for (int n = 0; n < 4; n++) oAcc[m][n][r] *= alpha;

                // scatter P (keys n*16+lo16) into swizzled per-wave A-frag tile
                char* pb = (char*)Ps + (wave << 12) + (ql << 7) + ((lo16 & 7) << 1);
                const int kb3 = lo16 >> 3;
                const int swp = (ql & 7) ^ (((ql >> 3) & 3) << 1);
                *(_Float16*)(pb + ((((0 + kb3) ^ swp) & 7) << 4)) = (_Float16)p0;
                *(_Float16*)(pb + ((((2 + kb3) ^ swp) & 7) << 4)) = (_Float16)p1;
                *(_Float16*)(pb + ((((4 + kb3) ^ swp) & 7) << 4)) = (_Float16)p2;
                *(_Float16*)(pb + ((((6 + kb3) ^ swp) & 7) << 4)) = (_Float16)p3;
            }

        // ---- O += P V ----
#pragma unroll
        for (int ks = 0; ks < 2; ks++) {
            f16x8 pa[2];
#pragma unroll
            for (int m = 0; m < 2; m++) {
                const int qlr = m * 16 + lo16;
                const int swp = (qlr & 7) ^ (((qlr >> 3) & 3) << 1);
                pa[m] = *(const f16x8*)((char*)Ps + (wave << 12) + (qlr << 7)
                                        + ((((ks * 4 + hi4) ^ swp) & 7) << 4));
            }
#pragma unroll
            for (int n = 0; n < 4; n++) {
                const int dv = n * 16 + lo16;
                const int swv = (dv & 7) ^ ((dv >> 3) & 7);
                f16x8 vf = *(const f16x8*)((char*)Vt + (dv << 7)
                                           + ((((ks * 4 + hi4) ^ swv) & 7) << 4));
                oAcc[0][n] = __builtin_amdgcn_mfma_f32_16x16x32_f16(pa[0], vf, oAcc[0][n], 0, 0, 0);
                oAcc[1][n] = __builtin_amdgcn_mfma_f32_16x16x32_f16(pa[1], vf, oAcc[1][n], 0, 0, 0);
            }
        }
    }

    // ---- epilogue: O / l -> fp16 [b,h,s,d] ----
#pragma unroll
    for (int m = 0; m < 2; m++)
#pragma unroll
        for (int r = 0; r < 4; r++) {
            const float inv = 1.f / lRow[m][r];
            const int q = q0 + m * 16 + hi4 * 4 + r;
#pragma unroll
            for (int n = 0; n < 4; n++)
                attnOut[((size_t)bh * SL + q) * HD + n * 16 + lo16] =
                    (_Float16)(oAcc[m][n][r] * inv);
        }
}

extern "C" void kernel_launch(void* const* d_in, const int* in_sizes, int n_in,
                              void* d_out, int out_size, void* d_ws, size_t ws_size,
                              hipStream_t stream)
{
    (void)in_sizes; (void)n_in; (void)out_size; (void)ws_size;

    const float* x    = (const float*)d_in[0];
    const float* bias = (const float*)d_in[1];
    const float* Wq   = (const float*)d_in[2];
    const float* Wk   = (const float*)d_in[3];
    const float* Wv   = (const float*)d_in[4];
    const float* Wo   = (const float*)d_in[5];

    const size_t nQKV = (size_t)BS * NH * SL * HD;   // 8388608 elements
    _Float16* Qh = (_Float16*)d_out;
    _Float16* Kh = Qh + nQKV;
    _Float16* Vh = (_Float16*)d_ws;
    _Float16* attnH = Vh + nQKV;

    // 1) QKV projections: [8192x1024] @ W^T -> fp16 [b,h,s,d]
    dim3 gq(ED / 64, (BS * SL) / 64, 3);
    qkv_kernel<<<gq, 256, 0, stream>>>(x, Wq, Wk, Wv, Qh, Kh, Vh);

    // 2) MFMA flash attention with rel-pos bias -> fp16 [b,h,s,d]
    dim3 ga(BS, SL / 128, NH);
    attn_kernel<<<ga, 256, 0, stream>>>(Qh, Kh, Vh, bias, attnH);

    // 3) output projection (gather A from [b,h,s,d]) -> d_out fp32 [8192x1024]
    dim3 go(ED / 64, (BS * SL) / 64);
    oproj_kernel<<<go, 256, 0, stream>>>(attnH, Wo, (float*)d_out);
}

// Round 2
// 747.616 us; speedup vs baseline: 7.2490x; 1.0783x over previous
//
#include <hip/hip_runtime.h>
#include <hip/hip_bf16.h>

#define NH 16
#define HD 64
#define ED 1024
#define BS 4
#define SL 2048

typedef _Float16 f16x8 __attribute__((ext_vector_type(8)));
typedef _Float16 f16x4 __attribute__((ext_vector_type(4)));
typedef _Float16 f16x2 __attribute__((ext_vector_type(2)));
typedef float floatx4 __attribute__((ext_vector_type(4)));

// ---------------------------------------------------------------------------
// Weight pre-convert: fp32 [ED][ED] -> fp16, for Wq/Wk/Wv (into ws slotB,
// which is later reused as attnOut once the weights are consumed).
// ---------------------------------------------------------------------------
__global__ __launch_bounds__(256) void cvtw_kernel(const float* __restrict__ Wq,
                                                   const float* __restrict__ Wk,
                                                   const float* __restrict__ Wv,
                                                   _Float16* __restrict__ Wh)
{
    const float* W = (blockIdx.y == 0) ? Wq : (blockIdx.y == 1) ? Wk : Wv;
    _Float16* out = Wh + (size_t)blockIdx.y * (ED * ED);
    const int i = (blockIdx.x * 256 + threadIdx.x) * 4;
    float4 v = *(const float4*)(W + i);
    f16x4 c;
    c[0] = (_Float16)v.x; c[1] = (_Float16)v.y;
    c[2] = (_Float16)v.z; c[3] = (_Float16)v.w;
    *(f16x4*)(out + i) = c;
}

// ---------------------------------------------------------------------------
// GEMM: C = A[MxK] * B[NxK]^T, 128x128 tile per 256-thread block.
// 4 waves 2x2; each wave a 64x64 sub-tile = 4x4 frags of 16x16x32 MFMA
// (16 MFMA per wave per K-step of 32 -> 4x the MFMA:staging ratio of the
// old 64x64 version).
// LDS fragment-contiguous: halves offset (kq*128 + rc)*8, byte addr
// XOR'd with kq<<5 so staging writes are <=2-way bank conflicts while
// b128 frag reads stay conflict-free (kq==hi4 uniform per 16-lane group).
// A_MODE 0: A fp32 row-major [M x K] (reg-stage + cvt)
// A_MODE 1: A fp16 [b,h,s,d] gather (row=b*SL+s, k=h*64+d)
// B_MODE 0: B fp16 row-major [N x K]
// B_MODE 1: B fp32 row-major [N x K] (reg-stage + cvt)
// OUT_MODE 0: fp16 scatter to [b,h,s,d];  OUT_MODE 1: fp32 [M x N]
// ---------------------------------------------------------------------------
__device__ __forceinline__ int lds_boff(int kq, int rc)
{
    return (((kq << 7) + rc) << 4) ^ (kq << 5);   // byte offset
}

template <int A_MODE, int B_MODE, int OUT_MODE>
__device__ __forceinline__ void gemm128_body(const float* __restrict__ Af,
                                             const _Float16* __restrict__ Ah,
                                             const float* __restrict__ Bf,
                                             const _Float16* __restrict__ Bh,
                                             _Float16* __restrict__ outH,
                                             float* __restrict__ outF,
                                             int K, int N)
{
    __shared__ __align__(16) _Float16 As[4 * 128 * 8];   // 8 KB
    __shared__ __align__(16) _Float16 Bs[4 * 128 * 8];   // 8 KB

    const int tid  = threadIdx.x;
    const int wave = tid >> 6;
    const int lane = tid & 63;
    const int lo16 = lane & 15;
    const int hi4  = lane >> 4;
    const int wm = wave >> 1;
    const int wn = wave & 1;
    const int rowTile = blockIdx.y * 128;
    const int colTile = blockIdx.x * 128;

    floatx4 acc[4][4];
#pragma unroll
    for (int m = 0; m < 4; m++)
#pragma unroll
        for (int n = 0; n < 4; n++)
            acc[m][n] = (floatx4){0.f, 0.f, 0.f, 0.f};

    for (int kb = 0; kb < K; kb += 32) {
        // ---- global -> regs (issued before barrier; latency overlaps) ----
        float4 aF[4]; f16x8 aH[2];
        if (A_MODE == 0) {
#pragma unroll
            for (int r = 0; r < 4; r++) {
                const int t2 = tid + r * 256;
                const int row = t2 >> 3;
                const int k4 = (t2 & 7) * 4;
                aF[r] = *(const float4*)(Af + (size_t)(rowTile + row) * K + kb + k4);
            }
        } else {
#pragma unroll
            for (int r = 0; r < 2; r++) {
                const int t2 = tid + r * 256;
                const int row = t2 >> 2;
                const int ko = (t2 & 3) * 8;
                const int gr = rowTile + row;
                const int b = gr >> 11;
                const int s = gr & (SL - 1);
                const int k0 = kb + ko;
                const int h = k0 >> 6;
                const int d = k0 & (HD - 1);
                aH[r] = *(const f16x8*)(Ah + (((size_t)(b * NH + h)) * SL + s) * HD + d);
            }
        }
        f16x8 bH[2]; float4 bF[4];
        if (B_MODE == 0) {
#pragma unroll
            for (int r = 0; r < 2; r++) {
                const int t2 = tid + r * 256;
                const int col = t2 >> 2;
                const int ko = (t2 & 3) * 8;
                bH[r] = *(const f16x8*)(Bh + (size_t)(colTile + col) * K + kb + ko);
            }
        } else {
#pragma unroll
            for (int r = 0; r < 4; r++) {
                const int t2 = tid + r * 256;
                const int col = t2 >> 3;
                const int k4 = (t2 & 7) * 4;
                bF[r] = *(const float4*)(Bf + (size_t)(colTile + col) * K + kb + k4);
            }
        }

        __syncthreads();                       // prior K-step frag reads done
        // ---- regs -> LDS ----
        if (A_MODE == 0) {
#pragma unroll
            for (int r = 0; r < 4; r++) {
                const int t2 = tid + r * 256;
                const int row = t2 >> 3;
                const int k4 = (t2 & 7) * 4;
                f16x4 c;
                c[0] = (_Float16)aF[r].x; c[1] = (_Float16)aF[r].y;
                c[2] = (_Float16)aF[r].z; c[3] = (_Float16)aF[r].w;
                *(f16x4*)((char*)As + lds_boff(k4 >> 3, row) + (k4 & 7) * 2) = c;
            }
        } else {
#pragma unroll
            for (int r = 0; r < 2; r++) {
                const int t2 = tid + r * 256;
                const int row = t2 >> 2;
                const int ko = (t2 & 3) * 8;
                *(f16x8*)((char*)As + lds_boff(ko >> 3, row)) = aH[r];
            }
        }
        if (B_MODE == 0) {
#pragma unroll
            for (int r = 0; r < 2; r++) {
                const int t2 = tid + r * 256;
                const int col = t2 >> 2;
                const int ko = (t2 & 3) * 8;
                *(f16x8*)((char*)Bs + lds_boff(ko >> 3, col)) = bH[r];
            }
        } else {
#pragma unroll
            for (int r = 0; r < 4; r++) {
                const int t2 = tid + r * 256;
                const int col = t2 >> 3;
                const int k4 = (t2 & 7) * 4;
                f16x4 c;
                c[0] = (_Float16)bF[r].x; c[1] = (_Float16)bF[r].y;
                c[2] = (_Float16)bF[r].z; c[3] = (_Float16)bF[r].w;
                *(f16x4*)((char*)Bs + lds_boff(k4 >> 3, col) + (k4 & 7) * 2) = c;
            }
        }
        __syncthreads();

        // ---- frags + 16 MFMA ----
        f16x8 af[4], bfr[4];
#pragma unroll
        for (int m = 0; m < 4; m++)
            af[m] = *(const f16x8*)((char*)As + lds_boff(hi4, wm * 64 + m * 16 + lo16));
#pragma unroll
        for (int n = 0; n < 4; n++)
            bfr[n] = *(const f16x8*)((char*)Bs + lds_boff(hi4, wn * 64 + n * 16 + lo16));
#pragma unroll
        for (int m = 0; m < 4; m++)
#pragma unroll
            for (int n = 0; n < 4; n++)
                acc[m][n] = __builtin_amdgcn_mfma_f32_16x16x32_f16(af[m], bfr[n], acc[m][n], 0, 0, 0);
    }

    // ---- epilogue: C/D layout col=lane&15, row=(lane>>4)*4+reg ----
#pragma unroll
    for (int m = 0; m < 4; m++) {
#pragma unroll
        for (int n = 0; n < 4; n++) {
            const int col = colTile + wn * 64 + n * 16 + lo16;
#pragma unroll
            for (int i = 0; i < 4; i++) {
                const int row = rowTile + wm * 64 + m * 16 + hi4 * 4 + i;
                float v = acc[m][n][i];
                if (OUT_MODE == 0) {
                    int b = row >> 11;
                    int s = row & (SL - 1);
                    int h = col >> 6;
                    int d = col & (HD - 1);
                    outH[(((size_t)(b * NH + h)) * SL + s) * HD + d] = (_Float16)v;
                } else {
                    outF[(size_t)row * N + col] = v;
                }
            }
        }
    }
}

__global__ __launch_bounds__(256) void qkv_kernel(const float* __restrict__ x,
                                                  const _Float16* __restrict__ Wh,
                                                  _Float16* __restrict__ Q,
                                                  _Float16* __restrict__ Kk,
                                                  _Float16* __restrict__ V)
{
    const _Float16* W = Wh + (size_t)blockIdx.z * (ED * ED);
    _Float16* out = (blockIdx.z == 0) ? Q : (blockIdx.z == 1) ? Kk : V;
    gemm128_body<0, 0, 0>(x, nullptr, nullptr, W, out, nullptr, ED, ED);
}

__global__ __launch_bounds__(256) void oproj_kernel(const _Float16* __restrict__ A,
                                                    const float* __restrict__ Wo,
                                                    float* __restrict__ out)
{
    gemm128_body<1, 1, 1>(nullptr, A, Wo, nullptr, nullptr, out, ED, ED);
}

// ---------------------------------------------------------------------------
// MFMA flash attention (unchanged from verified round-1 version).
// Block = 256 threads = 4 waves; q-tile 128 rows (wave owns 32 = 2 m-tiles).
// KV chunk = 64 keys. Per wave per chunk: 16 QK^T MFMAs + 16 PV MFMAs.
// ---------------------------------------------------------------------------
__global__ __launch_bounds__(256) void attn_kernel(const _Float16* __restrict__ Qg,
                                                   const _Float16* __restrict__ Kg,
                                                   const _Float16* __restrict__ Vg,
                                                   const float* __restrict__ bias,
                                                   _Float16* __restrict__ attnOut)
{
    __shared__ __align__(16) _Float16 Ks[8 * 64 * 8];    // 8 KB
    __shared__ __align__(16) _Float16 Vt[64 * 64];       // 8 KB
    __shared__ __align__(16) _Float16 Ps[4 * 32 * 64];   // 16 KB

    const int b  = blockIdx.x;
    const int qt = blockIdx.y;
    const int h  = blockIdx.z;
    const int bh = b * NH + h;
    const int tid  = threadIdx.x;
    const int wave = tid >> 6;
    const int lane = tid & 63;
    const int lo16 = lane & 15;
    const int hi4  = lane >> 4;

    const _Float16* Qbh = Qg + (size_t)bh * SL * HD;
    const _Float16* Kbh = Kg + (size_t)bh * SL * HD;
    const _Float16* Vbh = Vg + (size_t)bh * SL * HD;
    const float* biasH = bias + (size_t)h * SL * SL;

    const int q0 = qt * 128 + wave * 32;

    f16x8 qf[2][2];
#pragma unroll
    for (int m = 0; m < 2; m++)
#pragma unroll
        for (int ks = 0; ks < 2; ks++)
            qf[m][ks] = *(const f16x8*)(Qbh + (size_t)(q0 + m * 16 + lo16) * HD
                                        + ks * 32 + hi4 * 8);

    floatx4 oAcc[2][4];
    float mRow[2][4], lRow[2][4];
#pragma unroll
    for (int m = 0; m < 2; m++)
#pragma unroll
        for (int n = 0; n < 4; n++)
            oAcc[m][n] = (floatx4){0.f, 0.f, 0.f, 0.f};
#pragma unroll
    for (int m = 0; m < 2; m++)
#pragma unroll
        for (int r = 0; r < 4; r++) { mRow[m][r] = -1e30f; lRow[m][r] = 0.f; }

    const int kKey = tid >> 2;
    const int kD0  = (tid & 3) * 8;
    _Float16* kDst0 = Ks + (((kKey >> 4)     ) * 64 + (kKey & 15) + 16 * (kD0 >> 3)) * 8;
    _Float16* kDst1 = Ks + (((kKey >> 4) + 4) * 64 + (kKey & 15) + 16 * (kD0 >> 3)) * 8;

    const int vK0 = (tid >> 3) * 2;
    const int vD0 = (tid & 7) * 8;

    for (int kc = 0; kc < SL; kc += 64) {
        f16x8 ka = *(const f16x8*)(Kbh + (size_t)(kc + kKey) * HD + kD0);
        f16x8 kb = *(const f16x8*)(Kbh + (size_t)(kc + kKey) * HD + kD0 + 32);
        f16x8 va = *(const f16x8*)(Vbh + (size_t)(kc + vK0    ) * HD + vD0);
        f16x8 vb = *(const f16x8*)(Vbh + (size_t)(kc + vK0 + 1) * HD + vD0);

        __syncthreads();
        *(f16x8*)kDst0 = ka;
        *(f16x8*)kDst1 = kb;
#pragma unroll
        for (int i = 0; i < 8; i++) {
            const int d = vD0 + i;
            const int sw = (d & 7) ^ ((d >> 3) & 7);
            char* p = (char*)Vt + (d << 7)
                      + ((((vK0 >> 3) ^ sw) & 7) << 4) + ((vK0 & 7) << 1);
            f16x2 pr; pr[0] = va[i]; pr[1] = vb[i];
            *(f16x2*)p = pr;
        }
        __syncthreads();

        floatx4 s[2][4];
#pragma unroll
        for (int m = 0; m < 2; m++)
#pragma unroll
            for (int n = 0; n < 4; n++)
                s[m][n] = (floatx4){0.f, 0.f, 0.f, 0.f};
#pragma unroll
        for (int ks = 0; ks < 2; ks++)
#pragma unroll
            for (int n = 0; n < 4; n++) {
                f16x8 kf = *(const f16x8*)(Ks + ((ks * 4 + n) * 64 + lane) * 8);
                s[0][n] = __builtin_amdgcn_mfma_f32_16x16x32_f16(qf[0][ks], kf, s[0][n], 0, 0, 0);
                s[1][n] = __builtin_amdgcn_mfma_f32_16x16x32_f16(qf[1][ks], kf, s[1][n], 0, 0, 0);
            }

#pragma unroll
        for (int m = 0; m < 2; m++)
#pragma unroll
            for (int r = 0; r < 4; r++) {
                const int ql = m * 16 + hi4 * 4 + r;
                const float* bp = biasH + (size_t)(q0 + ql) * SL + kc + lo16;
                float s0 = s[m][0][r] + bp[0];
                float s1 = s[m][1][r] + bp[16];
                float s2 = s[m][2][r] + bp[32];
                float s3 = s[m][3][r] + bp[48];
                float rmax = fmaxf(fmaxf(s0, s1), fmaxf(s2, s3));
                rmax = fmaxf(rmax, __shfl_xor(rmax, 1));
                rmax = fmaxf(rmax, __shfl_xor(rmax, 2));
                rmax = fmaxf(rmax, __shfl_xor(rmax, 4));
                rmax = fmaxf(rmax, __shfl_xor(rmax, 8));
                const float mOld = mRow[m][r];
                const float mNew = fmaxf(mOld, rmax);
                const float alpha = __expf(mOld - mNew);
                mRow[m][r] = mNew;
                float p0 = __expf(s0 - mNew);
                float p1 = __expf(s1 - mNew);
                float p2 = __expf(s2 - mNew);
                float p3 = __expf(s3 - mNew);
                float rsum = (p0 + p1) + (p2 + p3);
                rsum += __shfl_xor(rsum, 1);
                rsum += __shfl_xor(rsum, 2);
                rsum += __shfl_xor(rsum, 4);
                rsum += __shfl_xor(rsum, 8);
                lRow[m][r] = lRow[m][r] * alpha + rsum;
#pragma unroll
                for (int n = 0; n < 4; n++) oAcc[m][n][r] *= alpha;

                char* pb = (char*)Ps + (wave << 12) + (ql << 7) + ((lo16 & 7) << 1);
                const int kb3 = lo16 >> 3;
                const int swp = (ql & 7) ^ (((ql >> 3) & 3) << 1);
                *(_Float16*)(pb + ((((0 + kb3) ^ swp) & 7) << 4)) = (_Float16)p0;
                *(_Float16*)(pb + ((((2 + kb3) ^ swp) & 7) << 4)) = (_Float16)p1;
                *(_Float16*)(pb + ((((4 + kb3) ^ swp) & 7) << 4)) = (_Float16)p2;
                *(_Float16*)(pb + ((((6 + kb3) ^ swp) & 7) << 4)) = (_Float16)p3;
            }

#pragma unroll
        for (int ks = 0; ks < 2; ks++) {
            f16x8 pa[2];
#pragma unroll
            for (int m = 0; m < 2; m++) {
                const int qlr = m * 16 + lo16;
                const int swp = (qlr & 7) ^ (((qlr >> 3) & 3) << 1);
                pa[m] = *(const f16x8*)((char*)Ps + (wave << 12) + (qlr << 7)
                                        + ((((ks * 4 + hi4) ^ swp) & 7) << 4));
            }
#pragma unroll
            for (int n = 0; n < 4; n++) {
                const int dv = n * 16 + lo16;
                const int swv = (dv & 7) ^ ((dv >> 3) & 7);
                f16x8 vf = *(const f16x8*)((char*)Vt + (dv << 7)
                                           + ((((ks * 4 + hi4) ^ swv) & 7) << 4));
                oAcc[0][n] = __builtin_amdgcn_mfma_f32_16x16x32_f16(pa[0], vf, oAcc[0][n], 0, 0, 0);
                oAcc[1][n] = __builtin_amdgcn_mfma_f32_16x16x32_f16(pa[1], vf, oAcc[1][n], 0, 0, 0);
            }
        }
    }

#pragma unroll
    for (int m = 0; m < 2; m++)
#pragma unroll
        for (int r = 0; r < 4; r++) {
            const float inv = 1.f / lRow[m][r];
            const int q = q0 + m * 16 + hi4 * 4 + r;
#pragma unroll
            for (int n = 0; n < 4; n++)
                attnOut[((size_t)bh * SL + q) * HD + n * 16 + lo16] =
                    (_Float16)(oAcc[m][n][r] * inv);
        }
}

extern "C" void kernel_launch(void* const* d_in, const int* in_sizes, int n_in,
                              void* d_out, int out_size, void* d_ws, size_t ws_size,
                              hipStream_t stream)
{
    (void)in_sizes; (void)n_in; (void)out_size; (void)ws_size;

    const float* x    = (const float*)d_in[0];
    const float* bias = (const float*)d_in[1];
    const float* Wq   = (const float*)d_in[2];
    const float* Wk   = (const float*)d_in[3];
    const float* Wv   = (const float*)d_in[4];
    const float* Wo   = (const float*)d_in[5];

    const size_t nQKV = (size_t)BS * NH * SL * HD;   // 8388608 elements
    // d_out: Q,K fp16 (2 x 16.78 MB). ws: [V 16.78MB][slotB 16.78MB].
    // slotB = Wh(q,k,v fp16, 6.3MB) during qkv; then attnH (16.78MB) after.
    _Float16* Qh = (_Float16*)d_out;
    _Float16* Kh = Qh + nQKV;
    _Float16* Vh = (_Float16*)d_ws;
    _Float16* slotB = Vh + nQKV;
    _Float16* Wh = slotB;
    _Float16* attnH = slotB;

    // 0) convert Wq/Wk/Wv to fp16
    cvtw_kernel<<<dim3(ED * ED / 1024, 3), 256, 0, stream>>>(Wq, Wk, Wv, Wh);

    // 1) QKV projections: [8192x1024] @ W^T -> fp16 [b,h,s,d]
    dim3 gq(ED / 128, (BS * SL) / 128, 3);
    qkv_kernel<<<gq, 256, 0, stream>>>(x, Wh, Qh, Kh, Vh);

    // 2) MFMA flash attention with rel-pos bias -> fp16 [b,h,s,d] (slotB)
    dim3 ga(BS, SL / 128, NH);
    attn_kernel<<<ga, 256, 0, stream>>>(Qh, Kh, Vh, bias, attnH);

    // 3) output projection (gather A from [b,h,s,d]) -> d_out fp32
    dim3 go(ED / 128, (BS * SL) / 128);
    oproj_kernel<<<go, 256, 0, stream>>>(attnH, Wo, (float*)d_out);
}